// Round 12
// baseline (228.803 us; speedup 1.0000x reference)
//
#include <hip/hip_runtime.h>

#define NEG_SLOPE 0.2f
#define EPSF 1e-16f
#define ABLK 512
#define SHIFT 8
#define SWZ4(e) (((e) << 5) | 0x1C)   // src = (lane&0x1C)|e  (groups of 4)
#define SWB(t)  (((t) << 8) | 0x07)   // src = (t<<3)|(lane&7) (edge-slot bcast)

using short8 = __attribute__((ext_vector_type(8))) short;
using f32x4  = __attribute__((ext_vector_type(4))) float;

__device__ __forceinline__ float lrelu_exp(float a) {
    a = (a > 0.f) ? a : NEG_SLOPE * a;
    return __expf(a);
}

__device__ __forceinline__ unsigned short f2bf(float f) {   // RNE
    unsigned u = __float_as_uint(f);
    u += 0x7fff + ((u >> 16) & 1);
    return (unsigned short)(u >> 16);
}

__device__ __forceinline__ float bf2f(unsigned short b) {
    return __uint_as_float(((unsigned)b) << 16);
}

__device__ __forceinline__ float bf_lo(unsigned pv) { return __uint_as_float(pv << 16); }
__device__ __forceinline__ float bf_hi(unsigned pv) { return __uint_as_float(pv & 0xffff0000u); }

template <int PAT>
__device__ __forceinline__ float swz_f(float v) {
    return __uint_as_float((unsigned)__builtin_amdgcn_ds_swizzle(__float_as_int(v), PAT));
}
template <int PAT>
__device__ __forceinline__ int swz_i(int v) {
    return __builtin_amdgcn_ds_swizzle(v, PAT);
}

// ---- fused: bhist (blocks [0,ABLK)) + W-prep (blocks [ABLK, ABLK+88)) --------
__global__ __launch_bounds__(256) void k_ph(const int* __restrict__ ei, int E, int N,
                                            int NBK, int* __restrict__ H,
                                            const float* __restrict__ W1,
                                            const float* __restrict__ W2,
                                            unsigned short* __restrict__ W1s,
                                            unsigned short* __restrict__ W2s) {
    __shared__ int hist[512];
    const int t = threadIdx.x;
    if (blockIdx.x < ABLK) {
        for (int i = t; i < NBK; i += 256) hist[i] = 0;
        __syncthreads();
        const int Et = E + N;
        for (int e = blockIdx.x * 256 + t; e < Et; e += ABLK * 256) {
            int d = (e < E) ? ei[E + e] : (e - E);
            atomicAdd(&hist[d >> SHIFT], 1);
        }
        __syncthreads();
        for (int i = t; i < NBK; i += 256)
            H[(size_t)i * ABLK + blockIdx.x] = hist[i];
        return;
    }
    const int tid = (blockIdx.x - ABLK) * 256 + t;
    if (tid < 16384) {                       // W1: 4kt x 8nt x 64l x 8e
        const int e  = tid & 7;
        const int l  = (tid >> 3) & 63;
        const int nt = (tid >> 9) & 7;
        const int kt = tid >> 12;
        const int k  = kt * 32 + ((l >> 4) * 8) + e;
        const int n  = nt * 16 + (l & 15);
        const float w = W1[k * 128 + n];
        const unsigned short hi = f2bf(w);
        const unsigned short lo = f2bf(w - bf2f(hi));
        const int idx = (kt * 8 + nt) * 512 + l * 8 + e;
        W1s[idx] = hi;
        W1s[16384 + idx] = lo;
    } else {                                 // W2: 4kt x 3nt x 64l x 8e (pad n>=40)
        const int t2 = tid - 16384;
        if (t2 >= 6144) return;
        const int e  = t2 & 7;
        const int l  = (t2 >> 3) & 63;
        const int g  = t2 >> 9;
        const int nt = g % 3;
        const int kt = g / 3;
        const int k  = kt * 32 + ((l >> 4) * 8) + e;
        const int n  = nt * 16 + (l & 15);
        const float w = (n < 40) ? W2[k * 40 + n] : 0.f;
        const unsigned short hi = f2bf(w);
        const unsigned short lo = f2bf(w - bf2f(hi));
        const int idx = (kt * 3 + nt) * 512 + l * 8 + e;
        W2s[idx] = hi;
        W2s[6144 + idx] = lo;
    }
}

__global__ __launch_bounds__(512) void k_scanH(int* __restrict__ H, int* __restrict__ BT) {
    __shared__ int sd[512];
    const int t = threadIdx.x;
    int* row = H + (size_t)blockIdx.x * ABLK;
    const int v = row[t];
    sd[t] = v;
    __syncthreads();
    for (int off = 1; off < 512; off <<= 1) {
        int add = (t >= off) ? sd[t - off] : 0;
        __syncthreads();
        sd[t] += add;
        __syncthreads();
    }
    row[t] = sd[t] - v;
    if (t == 511) BT[blockIdx.x] = sd[511];
}

__global__ __launch_bounds__(512) void k_scanBT(const int* __restrict__ BT,
                                                int* __restrict__ BB, int NBK) {
    __shared__ int sd[512];
    const int t = threadIdx.x;
    const int v = (t < NBK) ? BT[t] : 0;
    sd[t] = v;
    __syncthreads();
    for (int off = 1; off < 512; off <<= 1) {
        int add = (t >= off) ? sd[t - off] : 0;
        __syncthreads();
        sd[t] += add;
        __syncthreads();
    }
    if (t < NBK) BB[t] = sd[t] - v;
    if (t == 511) BB[NBK] = sd[511];
}

// ---- fused: bscat (blocks [0,ABLK)) + GEMM1-MFMA (blocks after, 256 rows/blk) -
__global__ __launch_bounds__(256) void k_sm(const int* __restrict__ ei, int E, int N,
                                            int NBK, const int* __restrict__ H,
                                            const int* __restrict__ BB,
                                            unsigned* __restrict__ E2,
                                            const float* __restrict__ x,
                                            const unsigned short* __restrict__ W1s,
                                            unsigned short* __restrict__ xhb) {
    __shared__ unsigned short Bs[32768];     // 64 KB (mm1); bscat aliases 4 KB
    const int t = threadIdx.x;

    if (blockIdx.x < ABLK) {
        // ---------------- bscat ----------------
        int* cnt  = (int*)Bs;
        int* base = (int*)Bs + 512;
        for (int i = t; i < NBK; i += 256) {
            cnt[i] = 0;
            base[i] = BB[i] + H[(size_t)i * ABLK + blockIdx.x];
        }
        __syncthreads();
        const int Et = E + N;
        for (int e = blockIdx.x * 256 + t; e < Et; e += ABLK * 256) {
            int s, d;
            if (e < E) { s = ei[e]; d = ei[E + e]; }
            else       { s = e - E; d = e - E; }
            const int b = d >> SHIFT;
            const int r = atomicAdd(&cnt[b], 1);
            E2[base[b] + r] = (unsigned)s | ((unsigned)(d & 255) << 24);
        }
        return;
    }

    // ---------------- GEMM1 (MFMA bf16x3), 256 rows per block ----------------
    for (int i = t; i < 4096; i += 256)
        ((uint4*)Bs)[i] = ((const uint4*)W1s)[i];
    __syncthreads();

    const int wm = t >> 6;
    const int l  = t & 63;
    const int cl = l & 15;
    const int blk0 = (blockIdx.x - ABLK) * 256;

    for (int g = 0; g < 4; ++g) {
        const int wrow0 = blk0 + g * 64 + wm * 16;
        const int arow = wrow0 + cl;
        const int rc = (arow < N) ? arow : (N - 1);

        short8 ah[4], al[4];
        #pragma unroll
        for (int kt = 0; kt < 4; ++kt) {
            const float* xp = x + (size_t)rc * 128 + kt * 32 + ((l >> 4) * 8);
            const float4 v0 = ((const float4*)xp)[0];
            const float4 v1 = ((const float4*)xp)[1];
            const float vv[8] = {v0.x, v0.y, v0.z, v0.w, v1.x, v1.y, v1.z, v1.w};
            #pragma unroll
            for (int e = 0; e < 8; ++e) {
                const unsigned short hi = f2bf(vv[e]);
                ((unsigned short*)&ah[kt])[e] = hi;
                ((unsigned short*)&al[kt])[e] = f2bf(vv[e] - bf2f(hi));
            }
        }

        f32x4 acc[8] = {};
        #pragma unroll
        for (int kt = 0; kt < 4; ++kt) {
            #pragma unroll
            for (int nt = 0; nt < 8; ++nt) {
                const short8 bh = *(const short8*)(Bs + (kt * 8 + nt) * 512 + l * 8);
                const short8 bl = *(const short8*)(Bs + 16384 + (kt * 8 + nt) * 512 + l * 8);
                acc[nt] = __builtin_amdgcn_mfma_f32_16x16x32_bf16(ah[kt], bh, acc[nt], 0, 0, 0);
                acc[nt] = __builtin_amdgcn_mfma_f32_16x16x32_bf16(ah[kt], bl, acc[nt], 0, 0, 0);
                acc[nt] = __builtin_amdgcn_mfma_f32_16x16x32_bf16(al[kt], bh, acc[nt], 0, 0, 0);
            }
        }

        const int rbase = wrow0 + ((l >> 4) * 4);
        #pragma unroll
        for (int reg = 0; reg < 4; ++reg) {
            const int orow = rbase + reg;
            if (orow < N) {
                #pragma unroll
                for (int nt = 0; nt < 8; ++nt)
                    xhb[(size_t)orow * 128 + nt * 16 + cl] = f2bf(acc[nt][reg]);
            }
        }
    }
}

// ---- fused: bcsr (blocks [0,NBK)) + esed1 (blocks [NBK, ...)) -----------------
__global__ __launch_bounds__(256) void k_ce(const unsigned* __restrict__ E2,
                                            const int* __restrict__ BB, int N,
                                            int* __restrict__ deg,
                                            int* __restrict__ rowp,
                                            int* __restrict__ csr, int NBK,
                                            const unsigned short* __restrict__ xhb,
                                            const float* __restrict__ asrc,
                                            const float* __restrict__ adst,
                                            float* __restrict__ es,
                                            float* __restrict__ ed) {
    __shared__ int cnt[256];
    __shared__ int sc[256];
    __shared__ int rp[256];
    __shared__ int fl[256];
    const int t = threadIdx.x;

    if (blockIdx.x >= NBK) {
        // ---------------- esed1 ----------------
        const int i = (blockIdx.x - NBK) * 256 + t;
        if (i >= N * 8) return;
        const int h = i & 7;
        const uint4* p = (const uint4*)(xhb + (size_t)i * 16);
        const uint4 q0 = p[0], q1 = p[1];
        const unsigned w[8] = {q0.x, q0.y, q0.z, q0.w, q1.x, q1.y, q1.z, q1.w};
        const float* av = asrc + h * 16;
        const float* bv = adst + h * 16;
        float s = 0.f, d = 0.f;
        #pragma unroll
        for (int j = 0; j < 8; ++j) {
            const float v0 = bf_lo(w[j]);
            const float v1 = bf_hi(w[j]);
            s += v0 * av[2 * j] + v1 * av[2 * j + 1];
            d += v0 * bv[2 * j] + v1 * bv[2 * j + 1];
        }
        es[i] = s; ed[i] = d;
        return;
    }

    // ---------------- bcsr ----------------
    const int b = blockIdx.x;
    const int lo = BB[b], hi = BB[b + 1];
    const int base_d = b << SHIFT;
    cnt[t] = 0; fl[t] = 0;
    __syncthreads();
    for (int i = lo + t; i < hi; i += 256)
        atomicAdd(&cnt[E2[i] >> 24], 1);
    __syncthreads();
    const int v = cnt[t];
    sc[t] = v;
    __syncthreads();
    for (int off = 1; off < 256; off <<= 1) {
        int add = (t >= off) ? sc[t - off] : 0;
        __syncthreads();
        sc[t] += add;
        __syncthreads();
    }
    rp[t] = sc[t] - v;
    const int d = base_d + t;
    if (d < N) { deg[d] = v; rowp[d] = lo + rp[t]; }
    __syncthreads();
    for (int i = lo + t; i < hi; i += 256) {
        const unsigned e = E2[i];
        const int ld = e >> 24;
        const int r = atomicAdd(&fl[ld], 1);
        csr[lo + rp[ld] + r] = (int)(e & 0xFFFFFFu);
    }
}

// ---- layer-1 aggregate: 8-edge tiles, 2 edges/step (halves), 4 ch/lane --------
// Phase A: lane = eA*8 + hA (eA = lane>>3, hA = lane&7).
// Phase B: half 0 processes edges k+t, half 1 edges k+4+t; lane's 4 channels =
// 16*hA + 4*q, q = (lane>>3)&3; swizzle src = (t<<3)|(lane&7) within each half.
__global__ __launch_bounds__(256) void k_l1(const unsigned short* __restrict__ xhb,
                                            const float* __restrict__ es,
                                            const float* __restrict__ ed,
                                            const int* __restrict__ rowp,
                                            const int* __restrict__ deg,
                                            const int* __restrict__ csr,
                                            const float* __restrict__ b1,
                                            unsigned short* __restrict__ hb, int N) {
    const int wave = threadIdx.x >> 6;
    const int lane = threadIdx.x & 63;
    const int n = blockIdx.x * 4 + wave;
    if (n >= N) return;
    const int hA = lane & 7;
    const int eA = lane >> 3;
    const float edv = ed[n * 8 + hA];
    const int start = rowp[n];
    const int cnt = deg[n];
    const int last = cnt - 1;
    const int q = (lane >> 3) & 3;
    const int boff = hA * 32 + q * 8;    // byte offset of this lane's 4 channels

    float4 acc = make_float4(0.f, 0.f, 0.f, 0.f);
    float dpart = 0.f;
    const char* xb = (const char*)xhb;

    for (int k = 0; k < cnt; k += 8) {
        const int ke = k + eA;
        const int idx = start + min(ke, last);
        const int s = csr[idx];
        float a = lrelu_exp(es[s * 8 + hA] + edv);
        a = (ke <= last) ? a : 0.f;
        dpart += a;
        const int soff = s << 8;
#define L1S(tt) { \
        const float ae = swz_f<SWB(tt)>(a); \
        const int   ro = swz_i<SWB(tt)>(soff); \
        const uint2 pv = *(const uint2*)(xb + (unsigned)(ro + boff)); \
        acc.x += ae * bf_lo(pv.x); \
        acc.y += ae * bf_hi(pv.x); \
        acc.z += ae * bf_lo(pv.y); \
        acc.w += ae * bf_hi(pv.y); }
        L1S(0) L1S(1) L1S(2) L1S(3)
#undef L1S
    }
    // dsum over 8 edge slots (lane bits 3,4,5) -> per-head total at lane&7
    dpart += __shfl_xor(dpart, 8, 64);
    dpart += __shfl_xor(dpart, 16, 64);
    dpart += __shfl_xor(dpart, 32, 64);
    // combine the two edge-halves of acc
    acc.x += __shfl_xor(acc.x, 32, 64);
    acc.y += __shfl_xor(acc.y, 32, 64);
    acc.z += __shfl_xor(acc.z, 32, 64);
    acc.w += __shfl_xor(acc.w, 32, 64);

    if (lane < 32) {
        const float inv = 1.f / (dpart + EPSF);
        const int ch = hA * 16 + q * 4;
        const float4 bb = *(const float4*)(b1 + ch);
        float o0 = acc.x * inv + bb.x;
        float o1 = acc.y * inv + bb.y;
        float o2 = acc.z * inv + bb.z;
        float o3 = acc.w * inv + bb.w;
        o0 = (o0 > 0.f) ? o0 : expm1f(o0);
        o1 = (o1 > 0.f) ? o1 : expm1f(o1);
        o2 = (o2 > 0.f) ? o2 : expm1f(o2);
        o3 = (o3 > 0.f) ? o3 : expm1f(o3);
        uint2 pk;
        pk.x = (unsigned)f2bf(o0) | ((unsigned)f2bf(o1) << 16);
        pk.y = (unsigned)f2bf(o2) | ((unsigned)f2bf(o3) << 16);
        *(uint2*)(hb + (size_t)n * 128 + ch) = pk;
    }
}

// ---- GEMM2 (MFMA, 256 rows/block) + fused e_src2/e_dst2 -----------------------
__global__ __launch_bounds__(256) void k_mm2(const unsigned short* __restrict__ h,
                                             const unsigned short* __restrict__ W2s,
                                             const float* __restrict__ as2,
                                             const float* __restrict__ ad2,
                                             unsigned short* __restrict__ xh2,
                                             float* __restrict__ es2,
                                             float* __restrict__ ed2, int N) {
    __shared__ unsigned short Bs[12288];     // 24 KB
    const int t = threadIdx.x;
    for (int i = t; i < 1536; i += 256)
        ((uint4*)Bs)[i] = ((const uint4*)W2s)[i];
    __syncthreads();

    const int wm = t >> 6;
    const int l  = t & 63;
    const int cl = l & 15;
    const float a0 = as2[cl],      d0v = ad2[cl];
    const float a1 = as2[16 + cl], d1v = ad2[16 + cl];
    const float a2 = (cl < 8) ? as2[32 + cl] : 0.f;
    const float d2v = (cl < 8) ? ad2[32 + cl] : 0.f;

    for (int g = 0; g < 4; ++g) {
        const int wrow0 = blockIdx.x * 256 + g * 64 + wm * 16;
        const int arow = wrow0 + cl;
        const int rc = (arow < N) ? arow : (N - 1);

        short8 a[4];
        #pragma unroll
        for (int kt = 0; kt < 4; ++kt)
            a[kt] = *(const short8*)(h + (size_t)rc * 128 + kt * 32 + ((l >> 4) * 8));

        f32x4 acc[3] = {};
        #pragma unroll
        for (int kt = 0; kt < 4; ++kt) {
            #pragma unroll
            for (int nt = 0; nt < 3; ++nt) {
                const short8 bh = *(const short8*)(Bs + (kt * 3 + nt) * 512 + l * 8);
                const short8 bl = *(const short8*)(Bs + 6144 + (kt * 3 + nt) * 512 + l * 8);
                acc[nt] = __builtin_amdgcn_mfma_f32_16x16x32_bf16(a[kt], bh, acc[nt], 0, 0, 0);
                acc[nt] = __builtin_amdgcn_mfma_f32_16x16x32_bf16(a[kt], bl, acc[nt], 0, 0, 0);
            }
        }

        const int rbase = wrow0 + ((l >> 4) * 4);
        #pragma unroll
        for (int reg = 0; reg < 4; ++reg) {
            const int orow = rbase + reg;
            if (orow < N) {
                #pragma unroll
                for (int nt = 0; nt < 3; ++nt) {
                    const int c = nt * 16 + cl;
                    if (c < 40)
                        xh2[(size_t)orow * 64 + c] = f2bf(acc[nt][reg]);
                }
            }
        }

        // fused e_src2/e_dst2 (single head): reduce over the 16-lane col group
        #pragma unroll
        for (int reg = 0; reg < 4; ++reg) {
            float ps = acc[0][reg] * a0 + acc[1][reg] * a1 + acc[2][reg] * a2;
            float pd = acc[0][reg] * d0v + acc[1][reg] * d1v + acc[2][reg] * d2v;
            ps += __shfl_xor(ps, 1, 64); ps += __shfl_xor(ps, 2, 64);
            ps += __shfl_xor(ps, 4, 64); ps += __shfl_xor(ps, 8, 64);
            pd += __shfl_xor(pd, 1, 64); pd += __shfl_xor(pd, 2, 64);
            pd += __shfl_xor(pd, 4, 64); pd += __shfl_xor(pd, 8, 64);
            const int row = rbase + reg;
            if (cl == reg && row < N) {
                es2[row] = ps;
                ed2[row] = pd;
            }
        }
    }
}

// ---- layer-2 aggregate: 2 nodes/wave, 4-edge tiles, bf16 padded rows ----------
__global__ __launch_bounds__(256) void k_l2(const unsigned short* __restrict__ xh2,
                                            const float* __restrict__ es2,
                                            const float* __restrict__ ed2,
                                            const int* __restrict__ rowp,
                                            const int* __restrict__ deg,
                                            const int* __restrict__ csr,
                                            const float* __restrict__ b2,
                                            float* __restrict__ out, int N) {
    const int wave = threadIdx.x >> 6;
    const int lane = threadIdx.x & 63;
    const int half = lane >> 5;
    const int n0 = blockIdx.x * 8 + wave * 2;
    if (n0 >= N) return;
    int n = n0 + half;
    const bool valid = (n < N);
    if (!valid) n = N - 1;
    const float edv = ed2[n];
    const int start = rowp[n];
    const int cnt = deg[n];
    const int last = cnt - 1;
    const int eA = lane & 3;
    const int c2 = lane & 31;
    const int cc4 = ((c2 < 20) ? c2 : 19) * 4;
    const char* xb = (const char*)xh2;
    const int cmax = max(cnt, __shfl_xor(cnt, 32, 64));

    float acc0 = 0.f, acc1 = 0.f, dpart = 0.f;
    for (int k = 0; k < cmax; k += 4) {
        const int ke = k + eA;
        const int idx = start + ((ke <= last) ? ke : last);
        const int s = csr[idx];
        const float a = (ke <= last) ? lrelu_exp(es2[s] + edv) : 0.f;
        dpart += a;
        const int soff = s << 7;
#define L2E(e) { \
        const float ae = swz_f<SWZ4(e)>(a); \
        const int   ro = swz_i<SWZ4(e)>(soff); \
        const unsigned pv = *(const unsigned*)(xb + (unsigned)(ro + cc4)); \
        acc0 += ae * bf_lo(pv); \
        acc1 += ae * bf_hi(pv); }
        L2E(0) L2E(1) L2E(2) L2E(3)
#undef L2E
    }
    dpart += __shfl_xor(dpart, 1, 64);
    dpart += __shfl_xor(dpart, 2, 64);

    if (valid && c2 < 20) {
        const float inv = 1.f / (dpart + EPSF);
        const float2 bb = *(const float2*)(b2 + c2 * 2);
        *(float2*)(out + (size_t)n * 40 + c2 * 2) =
            make_float2(acc0 * inv + bb.x, acc1 * inv + bb.y);
    }
}

extern "C" void kernel_launch(void* const* d_in, const int* in_sizes, int n_in,
                              void* d_out, int out_size, void* d_ws, size_t ws_size,
                              hipStream_t stream) {
    const float* x   = (const float*)d_in[0];
    const int*   ei  = (const int*)d_in[1];
    const float* W1  = (const float*)d_in[2];
    const float* as1 = (const float*)d_in[3];
    const float* ad1 = (const float*)d_in[4];
    const float* b1  = (const float*)d_in[5];
    const float* W2  = (const float*)d_in[6];
    const float* as2 = (const float*)d_in[7];
    const float* ad2 = (const float*)d_in[8];
    const float* b2  = (const float*)d_in[9];
    float* out = (float*)d_out;

    const int N    = in_sizes[0] / 128;
    const int E    = in_sizes[1] / 2;
    const int Et   = E + N;
    const int NBK  = (N + 255) >> SHIFT;
    const int GB256 = (N + 255) / 256;
    const int EB1  = (N * 8 + 255) / 256;

    // ---- workspace layout ----
    char* p = (char*)d_ws;
    unsigned short* W1s = (unsigned short*)p; p += 32768 * 2;   // 64 KB
    unsigned short* W2s = (unsigned short*)p; p += 12288 * 2;   // 24 KB
    unsigned short* xhb = (unsigned short*)p; p += (size_t)N * 128 * 2;
    float* es1  = (float*)p; p += (size_t)N * 8 * 4;
    float* ed1  = (float*)p; p += (size_t)N * 8 * 4;
    int*   deg  = (int*)p;   p += (size_t)N * 4;
    int*   rowp = (int*)p;   p += (size_t)N * 4;
    int*   csr  = (int*)p;   p += (size_t)Et * 4;
    int*   H    = (int*)p;   p += (size_t)512 * ABLK * 4;
    int*   BT   = (int*)p;   p += 512 * 4;
    int*   BB   = (int*)p;   p += 512 * 4;
    unsigned short* hbuf = (unsigned short*)p; p += (size_t)N * 128 * 2;
    unsigned short* xh2  = (unsigned short*)p; p += (size_t)N * 64 * 2;
    unsigned* E2 = (unsigned*)hbuf;   // 6.8 MB < 25.6 MB; dead after k_ce
    float* es2 = es1;
    float* ed2 = ed1;

    k_ph    <<<ABLK + 88,    256, 0, stream>>>(ei, E, N, NBK, H, W1, W2, W1s, W2s);
    k_scanH <<<NBK,          512, 0, stream>>>(H, BT);
    k_scanBT<<<1,            512, 0, stream>>>(BT, BB, NBK);
    k_sm    <<<ABLK + GB256, 256, 0, stream>>>(ei, E, N, NBK, H, BB, E2, x, W1s, xhb);
    k_ce    <<<NBK + EB1,    256, 0, stream>>>(E2, BB, N, deg, rowp, csr, NBK,
                                               xhb, as1, ad1, es1, ed1);
    k_l1    <<<(N + 3) / 4,  256, 0, stream>>>(xhb, es1, ed1, rowp, deg, csr, b1, hbuf, N);
    k_mm2   <<<GB256,        256, 0, stream>>>(hbuf, W2s, as2, ad2, xh2, es2, ed2, N);
    k_l2    <<<(N + 7) / 8,  256, 0, stream>>>(xh2, es2, ed2, rowp, deg, csr, b2, out, N);
}

// Round 13
// 216.766 us; speedup vs baseline: 1.0555x; 1.0555x over previous
//
#include <hip/hip_runtime.h>

#define NEG_SLOPE 0.2f
#define EPSF 1e-16f
#define ABLK 512
#define SHIFT 8
#define SWZ(e)  (((e) << 5) | 0x18)   // src = (lane&0x18)|e  (groups of 8)
#define SWZ4(e) (((e) << 5) | 0x1C)   // src = (lane&0x1C)|e  (groups of 4)

using short8 = __attribute__((ext_vector_type(8))) short;
using f32x4  = __attribute__((ext_vector_type(4))) float;

__device__ __forceinline__ float lrelu_exp(float a) {
    a = (a > 0.f) ? a : NEG_SLOPE * a;
    return __expf(a);
}

__device__ __forceinline__ unsigned short f2bf(float f) {   // RNE
    unsigned u = __float_as_uint(f);
    u += 0x7fff + ((u >> 16) & 1);
    return (unsigned short)(u >> 16);
}

__device__ __forceinline__ float bf2f(unsigned short b) {
    return __uint_as_float(((unsigned)b) << 16);
}

__device__ __forceinline__ float bf_lo(unsigned pv) { return __uint_as_float(pv << 16); }
__device__ __forceinline__ float bf_hi(unsigned pv) { return __uint_as_float(pv & 0xffff0000u); }

template <int PAT>
__device__ __forceinline__ float swz_f(float v) {
    return __uint_as_float((unsigned)__builtin_amdgcn_ds_swizzle(__float_as_int(v), PAT));
}
template <int PAT>
__device__ __forceinline__ int swz_i(int v) {
    return __builtin_amdgcn_ds_swizzle(v, PAT);
}

// ---- fused: bhist (blocks [0,ABLK)) + W-prep (blocks [ABLK, ABLK+88)) --------
__global__ __launch_bounds__(256) void k_ph(const int* __restrict__ ei, int E, int N,
                                            int NBK, int* __restrict__ H,
                                            const float* __restrict__ W1,
                                            const float* __restrict__ W2,
                                            unsigned short* __restrict__ W1s,
                                            unsigned short* __restrict__ W2s) {
    __shared__ int hist[512];
    const int t = threadIdx.x;
    if (blockIdx.x < ABLK) {
        for (int i = t; i < NBK; i += 256) hist[i] = 0;
        __syncthreads();
        const int Et = E + N;
        for (int e = blockIdx.x * 256 + t; e < Et; e += ABLK * 256) {
            int d = (e < E) ? ei[E + e] : (e - E);
            atomicAdd(&hist[d >> SHIFT], 1);
        }
        __syncthreads();
        for (int i = t; i < NBK; i += 256)
            H[(size_t)i * ABLK + blockIdx.x] = hist[i];
        return;
    }
    const int tid = (blockIdx.x - ABLK) * 256 + t;
    if (tid < 16384) {                       // W1: 4kt x 8nt x 64l x 8e
        const int e  = tid & 7;
        const int l  = (tid >> 3) & 63;
        const int nt = (tid >> 9) & 7;
        const int kt = tid >> 12;
        const int k  = kt * 32 + ((l >> 4) * 8) + e;
        const int n  = nt * 16 + (l & 15);
        const float w = W1[k * 128 + n];
        const unsigned short hi = f2bf(w);
        const unsigned short lo = f2bf(w - bf2f(hi));
        const int idx = (kt * 8 + nt) * 512 + l * 8 + e;
        W1s[idx] = hi;
        W1s[16384 + idx] = lo;
    } else {                                 // W2: 4kt x 3nt x 64l x 8e (pad n>=40)
        const int t2 = tid - 16384;
        if (t2 >= 6144) return;
        const int e  = t2 & 7;
        const int l  = (t2 >> 3) & 63;
        const int g  = t2 >> 9;
        const int nt = g % 3;
        const int kt = g / 3;
        const int k  = kt * 32 + ((l >> 4) * 8) + e;
        const int n  = nt * 16 + (l & 15);
        const float w = (n < 40) ? W2[k * 40 + n] : 0.f;
        const unsigned short hi = f2bf(w);
        const unsigned short lo = f2bf(w - bf2f(hi));
        const int idx = (kt * 3 + nt) * 512 + l * 8 + e;
        W2s[idx] = hi;
        W2s[6144 + idx] = lo;
    }
}

__global__ __launch_bounds__(512) void k_scanH(int* __restrict__ H, int* __restrict__ BT) {
    __shared__ int sd[512];
    const int t = threadIdx.x;
    int* row = H + (size_t)blockIdx.x * ABLK;
    const int v = row[t];
    sd[t] = v;
    __syncthreads();
    for (int off = 1; off < 512; off <<= 1) {
        int add = (t >= off) ? sd[t - off] : 0;
        __syncthreads();
        sd[t] += add;
        __syncthreads();
    }
    row[t] = sd[t] - v;
    if (t == 511) BT[blockIdx.x] = sd[511];
}

__global__ __launch_bounds__(512) void k_scanBT(const int* __restrict__ BT,
                                                int* __restrict__ BB, int NBK) {
    __shared__ int sd[512];
    const int t = threadIdx.x;
    const int v = (t < NBK) ? BT[t] : 0;
    sd[t] = v;
    __syncthreads();
    for (int off = 1; off < 512; off <<= 1) {
        int add = (t >= off) ? sd[t - off] : 0;
        __syncthreads();
        sd[t] += add;
        __syncthreads();
    }
    if (t < NBK) BB[t] = sd[t] - v;
    if (t == 511) BB[NBK] = sd[511];
}

// ---- fused: bscat (blocks [0,ABLK)) + GEMM1-MFMA (blocks [ABLK, ABLK+GBM)) ----
__global__ __launch_bounds__(256) void k_sm(const int* __restrict__ ei, int E, int N,
                                            int NBK, const int* __restrict__ H,
                                            const int* __restrict__ BB,
                                            unsigned* __restrict__ E2,
                                            const float* __restrict__ x,
                                            const unsigned short* __restrict__ W1s,
                                            unsigned short* __restrict__ xhb) {
    __shared__ unsigned short Bs[32768];     // 64 KB (mm1); bscat aliases 4 KB
    const int t = threadIdx.x;

    if (blockIdx.x < ABLK) {
        // ---------------- bscat ----------------
        int* cnt  = (int*)Bs;
        int* base = (int*)Bs + 512;
        for (int i = t; i < NBK; i += 256) {
            cnt[i] = 0;
            base[i] = BB[i] + H[(size_t)i * ABLK + blockIdx.x];
        }
        __syncthreads();
        const int Et = E + N;
        for (int e = blockIdx.x * 256 + t; e < Et; e += ABLK * 256) {
            int s, d;
            if (e < E) { s = ei[e]; d = ei[E + e]; }
            else       { s = e - E; d = e - E; }
            const int b = d >> SHIFT;
            const int r = atomicAdd(&cnt[b], 1);
            E2[base[b] + r] = (unsigned)s | ((unsigned)(d & 255) << 24);
        }
        return;
    }

    // ---------------- GEMM1 (MFMA bf16x3) ----------------
    for (int i = t; i < 4096; i += 256)
        ((uint4*)Bs)[i] = ((const uint4*)W1s)[i];

    const int wm = t >> 6;
    const int l  = t & 63;
    const int wrow0 = (blockIdx.x - ABLK) * 64 + wm * 16;
    const int arow = wrow0 + (l & 15);
    const int rc = (arow < N) ? arow : (N - 1);

    short8 ah[4], al[4];
    #pragma unroll
    for (int kt = 0; kt < 4; ++kt) {
        const float* xp = x + (size_t)rc * 128 + kt * 32 + ((l >> 4) * 8);
        const float4 v0 = ((const float4*)xp)[0];
        const float4 v1 = ((const float4*)xp)[1];
        const float vv[8] = {v0.x, v0.y, v0.z, v0.w, v1.x, v1.y, v1.z, v1.w};
        #pragma unroll
        for (int e = 0; e < 8; ++e) {
            const unsigned short hi = f2bf(vv[e]);
            ((unsigned short*)&ah[kt])[e] = hi;
            ((unsigned short*)&al[kt])[e] = f2bf(vv[e] - bf2f(hi));
        }
    }
    __syncthreads();

    f32x4 acc[8] = {};
    #pragma unroll
    for (int kt = 0; kt < 4; ++kt) {
        #pragma unroll
        for (int nt = 0; nt < 8; ++nt) {
            const short8 bh = *(const short8*)(Bs + (kt * 8 + nt) * 512 + l * 8);
            const short8 bl = *(const short8*)(Bs + 16384 + (kt * 8 + nt) * 512 + l * 8);
            acc[nt] = __builtin_amdgcn_mfma_f32_16x16x32_bf16(ah[kt], bh, acc[nt], 0, 0, 0);
            acc[nt] = __builtin_amdgcn_mfma_f32_16x16x32_bf16(ah[kt], bl, acc[nt], 0, 0, 0);
            acc[nt] = __builtin_amdgcn_mfma_f32_16x16x32_bf16(al[kt], bh, acc[nt], 0, 0, 0);
        }
    }

    const int cl = l & 15;
    const int rbase = wrow0 + ((l >> 4) * 4);
    #pragma unroll
    for (int reg = 0; reg < 4; ++reg) {
        const int orow = rbase + reg;
        if (orow < N) {
            #pragma unroll
            for (int nt = 0; nt < 8; ++nt)
                xhb[(size_t)orow * 128 + nt * 16 + cl] = f2bf(acc[nt][reg]);
        }
    }
}

// ---- fused: bcsr (blocks [0,NBK)) + esed1 (blocks [NBK, ...)) -----------------
__global__ __launch_bounds__(256) void k_ce(const unsigned* __restrict__ E2,
                                            const int* __restrict__ BB, int N,
                                            int* __restrict__ deg,
                                            int* __restrict__ rowp,
                                            int* __restrict__ csr, int NBK,
                                            const unsigned short* __restrict__ xhb,
                                            const float* __restrict__ asrc,
                                            const float* __restrict__ adst,
                                            float* __restrict__ es,
                                            float* __restrict__ ed) {
    __shared__ int cnt[256];
    __shared__ int sc[256];
    __shared__ int rp[256];
    __shared__ int fl[256];
    const int t = threadIdx.x;

    if (blockIdx.x >= NBK) {
        // ---------------- esed1 ----------------
        const int i = (blockIdx.x - NBK) * 256 + t;
        if (i >= N * 8) return;
        const int h = i & 7;
        const uint4* p = (const uint4*)(xhb + (size_t)i * 16);
        const uint4 q0 = p[0], q1 = p[1];
        const unsigned w[8] = {q0.x, q0.y, q0.z, q0.w, q1.x, q1.y, q1.z, q1.w};
        const float* av = asrc + h * 16;
        const float* bv = adst + h * 16;
        float s = 0.f, d = 0.f;
        #pragma unroll
        for (int j = 0; j < 8; ++j) {
            const float v0 = bf_lo(w[j]);
            const float v1 = bf_hi(w[j]);
            s += v0 * av[2 * j] + v1 * av[2 * j + 1];
            d += v0 * bv[2 * j] + v1 * bv[2 * j + 1];
        }
        es[i] = s; ed[i] = d;
        return;
    }

    // ---------------- bcsr ----------------
    const int b = blockIdx.x;
    const int lo = BB[b], hi = BB[b + 1];
    const int base_d = b << SHIFT;
    cnt[t] = 0; fl[t] = 0;
    __syncthreads();
    for (int i = lo + t; i < hi; i += 256)
        atomicAdd(&cnt[E2[i] >> 24], 1);
    __syncthreads();
    const int v = cnt[t];
    sc[t] = v;
    __syncthreads();
    for (int off = 1; off < 256; off <<= 1) {
        int add = (t >= off) ? sc[t - off] : 0;
        __syncthreads();
        sc[t] += add;
        __syncthreads();
    }
    rp[t] = sc[t] - v;
    const int d = base_d + t;
    if (d < N) { deg[d] = v; rowp[d] = lo + rp[t]; }
    __syncthreads();
    for (int i = lo + t; i < hi; i += 256) {
        const unsigned e = E2[i];
        const int ld = e >> 24;
        const int r = atomicAdd(&fl[ld], 1);
        csr[lo + rp[ld] + r] = (int)(e & 0xFFFFFFu);
    }
}

// -------- layer-1 aggregate: 8-edge tiles, 2-phase (R8/R10 proven form) --------
__global__ __launch_bounds__(256) void k_l1(const unsigned short* __restrict__ xhb,
                                            const float* __restrict__ es,
                                            const float* __restrict__ ed,
                                            const int* __restrict__ rowp,
                                            const int* __restrict__ deg,
                                            const int* __restrict__ csr,
                                            const float* __restrict__ b1,
                                            unsigned short* __restrict__ hb, int N) {
    const int wave = threadIdx.x >> 6;
    const int lane = threadIdx.x & 63;
    const int n = blockIdx.x * 4 + wave;
    if (n >= N) return;
    const int hA = lane >> 3;
    const int eA = lane & 7;
    const float edv = ed[n * 8 + hA];
    const int start = rowp[n];
    const int cnt = deg[n];
    const int last = cnt - 1;
    const int lane4 = lane * 4;

    float acc0 = 0.f, acc1 = 0.f, dpart = 0.f;
    const char* xb = (const char*)xhb;

    for (int k = 0; k < cnt; k += 8) {
        const int ke = k + eA;
        const int idx = start + min(ke, last);
        const int s = csr[idx];
        float a = lrelu_exp(es[s * 8 + hA] + edv);
        a = (ke <= last) ? a : 0.f;
        dpart += a;
        const int soff = s << 8;
#define L1E(e) { \
        const float ae = swz_f<SWZ(e)>(a); \
        const int   ro = swz_i<SWZ(e)>(soff); \
        const unsigned pv = *(const unsigned*)(xb + (unsigned)(ro + lane4)); \
        acc0 += ae * bf_lo(pv); \
        acc1 += ae * bf_hi(pv); }
        L1E(0) L1E(1) L1E(2) L1E(3) L1E(4) L1E(5) L1E(6) L1E(7)
#undef L1E
    }
    dpart += __shfl_xor(dpart, 1, 64);
    dpart += __shfl_xor(dpart, 2, 64);
    dpart += __shfl_xor(dpart, 4, 64);

    const float inv = 1.f / (dpart + EPSF);
    const float2 bb = *(const float2*)(b1 + lane * 2);
    float o0 = acc0 * inv + bb.x;
    float o1 = acc1 * inv + bb.y;
    o0 = (o0 > 0.f) ? o0 : expm1f(o0);
    o1 = (o1 > 0.f) ? o1 : expm1f(o1);
    const unsigned pk = (unsigned)f2bf(o0) | ((unsigned)f2bf(o1) << 16);
    *(unsigned*)(hb + (size_t)n * 128 + lane * 2) = pk;
}

// ---- GEMM2 (MFMA, 64 rows/block) + fused e_src2/e_dst2 from f32 accs ----------
__global__ __launch_bounds__(256) void k_mm2(const unsigned short* __restrict__ h,
                                             const unsigned short* __restrict__ W2s,
                                             const float* __restrict__ as2,
                                             const float* __restrict__ ad2,
                                             unsigned short* __restrict__ xh2,
                                             float* __restrict__ es2,
                                             float* __restrict__ ed2, int N) {
    __shared__ unsigned short Bs[12288];     // 24 KB
    const int t = threadIdx.x;
    for (int i = t; i < 1536; i += 256)
        ((uint4*)Bs)[i] = ((const uint4*)W2s)[i];

    const int wm = t >> 6;
    const int l  = t & 63;
    const int wrow0 = blockIdx.x * 64 + wm * 16;
    const int arow = wrow0 + (l & 15);
    const int rc = (arow < N) ? arow : (N - 1);

    short8 a[4];
    #pragma unroll
    for (int kt = 0; kt < 4; ++kt)
        a[kt] = *(const short8*)(h + (size_t)rc * 128 + kt * 32 + ((l >> 4) * 8));
    __syncthreads();

    f32x4 acc[3] = {};
    #pragma unroll
    for (int kt = 0; kt < 4; ++kt) {
        #pragma unroll
        for (int nt = 0; nt < 3; ++nt) {
            const short8 bh = *(const short8*)(Bs + (kt * 3 + nt) * 512 + l * 8);
            const short8 bl = *(const short8*)(Bs + 6144 + (kt * 3 + nt) * 512 + l * 8);
            acc[nt] = __builtin_amdgcn_mfma_f32_16x16x32_bf16(a[kt], bh, acc[nt], 0, 0, 0);
            acc[nt] = __builtin_amdgcn_mfma_f32_16x16x32_bf16(a[kt], bl, acc[nt], 0, 0, 0);
        }
    }

    const int cl = l & 15;
    const int rbase = wrow0 + ((l >> 4) * 4);
    #pragma unroll
    for (int reg = 0; reg < 4; ++reg) {
        const int orow = rbase + reg;
        if (orow < N) {
            #pragma unroll
            for (int nt = 0; nt < 3; ++nt) {
                const int c = nt * 16 + cl;
                if (c < 40)
                    xh2[(size_t)orow * 64 + c] = f2bf(acc[nt][reg]);
            }
        }
    }

    // fused e_src2/e_dst2 (single head): reduce over the 16-lane col group
    const float a0 = as2[cl],      d0v = ad2[cl];
    const float a1 = as2[16 + cl], d1v = ad2[16 + cl];
    const float a2 = (cl < 8) ? as2[32 + cl] : 0.f;
    const float d2v = (cl < 8) ? ad2[32 + cl] : 0.f;
    #pragma unroll
    for (int reg = 0; reg < 4; ++reg) {
        float ps = acc[0][reg] * a0 + acc[1][reg] * a1 + acc[2][reg] * a2;
        float pd = acc[0][reg] * d0v + acc[1][reg] * d1v + acc[2][reg] * d2v;
        ps += __shfl_xor(ps, 1, 64); ps += __shfl_xor(ps, 2, 64);
        ps += __shfl_xor(ps, 4, 64); ps += __shfl_xor(ps, 8, 64);
        pd += __shfl_xor(pd, 1, 64); pd += __shfl_xor(pd, 2, 64);
        pd += __shfl_xor(pd, 4, 64); pd += __shfl_xor(pd, 8, 64);
        const int row = rbase + reg;
        if (cl == reg && row < N) {
            es2[row] = ps;
            ed2[row] = pd;
        }
    }
}

// ---- layer-2 aggregate: 2 nodes/wave, 4-edge tiles, bf16 padded rows ----------
__global__ __launch_bounds__(256) void k_l2(const unsigned short* __restrict__ xh2,
                                            const float* __restrict__ es2,
                                            const float* __restrict__ ed2,
                                            const int* __restrict__ rowp,
                                            const int* __restrict__ deg,
                                            const int* __restrict__ csr,
                                            const float* __restrict__ b2,
                                            float* __restrict__ out, int N) {
    const int wave = threadIdx.x >> 6;
    const int lane = threadIdx.x & 63;
    const int half = lane >> 5;
    const int n0 = blockIdx.x * 8 + wave * 2;
    if (n0 >= N) return;
    int n = n0 + half;
    const bool valid = (n < N);
    if (!valid) n = N - 1;
    const float edv = ed2[n];
    const int start = rowp[n];
    const int cnt = deg[n];
    const int last = cnt - 1;
    const int eA = lane & 3;
    const int c2 = lane & 31;
    const int cc4 = ((c2 < 20) ? c2 : 19) * 4;
    const char* xb = (const char*)xh2;
    const int cmax = max(cnt, __shfl_xor(cnt, 32, 64));

    float acc0 = 0.f, acc1 = 0.f, dpart = 0.f;
    for (int k = 0; k < cmax; k += 4) {
        const int ke = k + eA;
        const int idx = start + ((ke <= last) ? ke : last);
        const int s = csr[idx];
        const float a = (ke <= last) ? lrelu_exp(es2[s] + edv) : 0.f;
        dpart += a;
        const int soff = s << 7;
#define L2E(e) { \
        const float ae = swz_f<SWZ4(e)>(a); \
        const int   ro = swz_i<SWZ4(e)>(soff); \
        const unsigned pv = *(const unsigned*)(xb + (unsigned)(ro + cc4)); \
        acc0 += ae * bf_lo(pv); \
        acc1 += ae * bf_hi(pv); }
        L2E(0) L2E(1) L2E(2) L2E(3)
#undef L2E
    }
    dpart += __shfl_xor(dpart, 1, 64);
    dpart += __shfl_xor(dpart, 2, 64);

    if (valid && c2 < 20) {
        const float inv = 1.f / (dpart + EPSF);
        const float2 bb = *(const float2*)(b2 + c2 * 2);
        *(float2*)(out + (size_t)n * 40 + c2 * 2) =
            make_float2(acc0 * inv + bb.x, acc1 * inv + bb.y);
    }
}

extern "C" void kernel_launch(void* const* d_in, const int* in_sizes, int n_in,
                              void* d_out, int out_size, void* d_ws, size_t ws_size,
                              hipStream_t stream) {
    const float* x   = (const float*)d_in[0];
    const int*   ei  = (const int*)d_in[1];
    const float* W1  = (const float*)d_in[2];
    const float* as1 = (const float*)d_in[3];
    const float* ad1 = (const float*)d_in[4];
    const float* b1  = (const float*)d_in[5];
    const float* W2  = (const float*)d_in[6];
    const float* as2 = (const float*)d_in[7];
    const float* ad2 = (const float*)d_in[8];
    const float* b2  = (const float*)d_in[9];
    float* out = (float*)d_out;

    const int N   = in_sizes[0] / 128;
    const int E   = in_sizes[1] / 2;
    const int Et  = E + N;
    const int NBK = (N + 255) >> SHIFT;
    const int GBM = (N + 63) / 64;
    const int EB1 = (N * 8 + 255) / 256;

    // ---- workspace layout ----
    char* p = (char*)d_ws;
    unsigned short* W1s = (unsigned short*)p; p += 32768 * 2;   // 64 KB
    unsigned short* W2s = (unsigned short*)p; p += 12288 * 2;   // 24 KB
    unsigned short* xhb = (unsigned short*)p; p += (size_t)N * 128 * 2;
    float* es1  = (float*)p; p += (size_t)N * 8 * 4;
    float* ed1  = (float*)p; p += (size_t)N * 8 * 4;
    int*   deg  = (int*)p;   p += (size_t)N * 4;
    int*   rowp = (int*)p;   p += (size_t)N * 4;
    int*   csr  = (int*)p;   p += (size_t)Et * 4;
    int*   H    = (int*)p;   p += (size_t)512 * ABLK * 4;
    int*   BT   = (int*)p;   p += 512 * 4;
    int*   BB   = (int*)p;   p += 512 * 4;
    unsigned short* hbuf = (unsigned short*)p; p += (size_t)N * 128 * 2;
    unsigned short* xh2  = (unsigned short*)p; p += (size_t)N * 64 * 2;
    unsigned* E2 = (unsigned*)hbuf;   // 6.8 MB < 25.6 MB; dead after k_ce
    float* es2 = es1;
    float* ed2 = ed1;

    k_ph    <<<ABLK + 88,    256, 0, stream>>>(ei, E, N, NBK, H, W1, W2, W1s, W2s);
    k_scanH <<<NBK,          512, 0, stream>>>(H, BT);
    k_scanBT<<<1,            512, 0, stream>>>(BT, BB, NBK);
    k_sm    <<<ABLK + GBM,   256, 0, stream>>>(ei, E, N, NBK, H, BB, E2, x, W1s, xhb);
    k_ce    <<<NBK + EB1,    256, 0, stream>>>(E2, BB, N, deg, rowp, csr, NBK,
                                               xhb, as1, ad1, es1, ed1);
    k_l1    <<<(N + 3) / 4,  256, 0, stream>>>(xhb, es1, ed1, rowp, deg, csr, b1, hbuf, N);
    k_mm2   <<<GBM,          256, 0, stream>>>(hbuf, W2s, as2, ad2, xh2, es2, ed2, N);
    k_l2    <<<(N + 7) / 8,  256, 0, stream>>>(xh2, es2, ed2, rowp, deg, csr, b2, out, N);
}

// Round 15
// 215.952 us; speedup vs baseline: 1.0595x; 1.0038x over previous
//
#include <hip/hip_runtime.h>

#define NEG_SLOPE 0.2f
#define EPSF 1e-16f
#define ABLK 512
#define SHIFT 8
#define PADSLACK 2048                 // >= 256 dsts * 7 max pad per bucket
#define SWZ(e)  (((e) << 5) | 0x18)   // src = (lane&0x18)|e  (groups of 8)
#define SWZ4(e) (((e) << 5) | 0x1C)   // src = (lane&0x1C)|e  (groups of 4)

using short8 = __attribute__((ext_vector_type(8))) short;
using f32x4  = __attribute__((ext_vector_type(4))) float;

__device__ __forceinline__ float lrelu_exp(float a) {
    a = (a > 0.f) ? a : NEG_SLOPE * a;
    return __expf(a);
}

__device__ __forceinline__ unsigned short f2bf(float f) {   // RNE
    unsigned u = __float_as_uint(f);
    u += 0x7fff + ((u >> 16) & 1);
    return (unsigned short)(u >> 16);
}

__device__ __forceinline__ float bf2f(unsigned short b) {
    return __uint_as_float(((unsigned)b) << 16);
}

__device__ __forceinline__ float bf_lo(unsigned pv) { return __uint_as_float(pv << 16); }
__device__ __forceinline__ float bf_hi(unsigned pv) { return __uint_as_float(pv & 0xffff0000u); }

template <int PAT>
__device__ __forceinline__ float swz_f(float v) {
    return __uint_as_float((unsigned)__builtin_amdgcn_ds_swizzle(__float_as_int(v), PAT));
}
template <int PAT>
__device__ __forceinline__ int swz_i(int v) {
    return __builtin_amdgcn_ds_swizzle(v, PAT);
}

// ---- fused: bhist (blocks [0,ABLK)) + W-prep (blocks [ABLK, ABLK+88)) --------
__global__ __launch_bounds__(256) void k_ph(const int* __restrict__ ei, int E, int N,
                                            int NBK, int* __restrict__ H,
                                            const float* __restrict__ W1,
                                            const float* __restrict__ W2,
                                            unsigned short* __restrict__ W1s,
                                            unsigned short* __restrict__ W2s) {
    __shared__ int hist[512];
    const int t = threadIdx.x;
    if (blockIdx.x < ABLK) {
        for (int i = t; i < NBK; i += 256) hist[i] = 0;
        __syncthreads();
        const int Et = E + N;
        for (int e = blockIdx.x * 256 + t; e < Et; e += ABLK * 256) {
            int d = (e < E) ? ei[E + e] : (e - E);
            atomicAdd(&hist[d >> SHIFT], 1);
        }
        __syncthreads();
        for (int i = t; i < NBK; i += 256)
            H[(size_t)i * ABLK + blockIdx.x] = hist[i];
        return;
    }
    const int tid = (blockIdx.x - ABLK) * 256 + t;
    if (tid < 16384) {                       // W1: 4kt x 8nt x 64l x 8e
        const int e  = tid & 7;
        const int l  = (tid >> 3) & 63;
        const int nt = (tid >> 9) & 7;
        const int kt = tid >> 12;
        const int k  = kt * 32 + ((l >> 4) * 8) + e;
        const int n  = nt * 16 + (l & 15);
        const float w = W1[k * 128 + n];
        const unsigned short hi = f2bf(w);
        const unsigned short lo = f2bf(w - bf2f(hi));
        const int idx = (kt * 8 + nt) * 512 + l * 8 + e;
        W1s[idx] = hi;
        W1s[16384 + idx] = lo;
    } else {                                 // W2: 4kt x 3nt x 64l x 8e (pad n>=40)
        const int t2 = tid - 16384;
        if (t2 >= 6144) return;
        const int e  = t2 & 7;
        const int l  = (t2 >> 3) & 63;
        const int g  = t2 >> 9;
        const int nt = g % 3;
        const int kt = g / 3;
        const int k  = kt * 32 + ((l >> 4) * 8) + e;
        const int n  = nt * 16 + (l & 15);
        const float w = (n < 40) ? W2[k * 40 + n] : 0.f;
        const unsigned short hi = f2bf(w);
        const unsigned short lo = f2bf(w - bf2f(hi));
        const int idx = (kt * 3 + nt) * 512 + l * 8 + e;
        W2s[idx] = hi;
        W2s[6144 + idx] = lo;
    }
}

__global__ __launch_bounds__(512) void k_scanH(int* __restrict__ H, int* __restrict__ BT) {
    __shared__ int sd[512];
    const int t = threadIdx.x;
    int* row = H + (size_t)blockIdx.x * ABLK;
    const int v = row[t];
    sd[t] = v;
    __syncthreads();
    for (int off = 1; off < 512; off <<= 1) {
        int add = (t >= off) ? sd[t - off] : 0;
        __syncthreads();
        sd[t] += add;
        __syncthreads();
    }
    row[t] = sd[t] - v;
    if (t == 511) BT[blockIdx.x] = sd[511];
}

__global__ __launch_bounds__(512) void k_scanBT(const int* __restrict__ BT,
                                                int* __restrict__ BB, int NBK) {
    __shared__ int sd[512];
    const int t = threadIdx.x;
    const int v = (t < NBK) ? BT[t] : 0;
    sd[t] = v;
    __syncthreads();
    for (int off = 1; off < 512; off <<= 1) {
        int add = (t >= off) ? sd[t - off] : 0;
        __syncthreads();
        sd[t] += add;
        __syncthreads();
    }
    if (t < NBK) BB[t] = sd[t] - v;
    if (t == 511) BB[NBK] = sd[511];
}

// ---- fused: bscat (blocks [0,ABLK)) + GEMM1-MFMA (blocks [ABLK, ABLK+GBM)) ----
__global__ __launch_bounds__(256) void k_sm(const int* __restrict__ ei, int E, int N,
                                            int NBK, const int* __restrict__ H,
                                            const int* __restrict__ BB,
                                            unsigned* __restrict__ E2,
                                            const float* __restrict__ x,
                                            const unsigned short* __restrict__ W1s,
                                            unsigned short* __restrict__ xhb) {
    __shared__ unsigned short Bs[32768];     // 64 KB (mm1); bscat aliases 4 KB
    const int t = threadIdx.x;

    if (blockIdx.x < ABLK) {
        // ---------------- bscat ----------------
        int* cnt  = (int*)Bs;
        int* base = (int*)Bs + 512;
        for (int i = t; i < NBK; i += 256) {
            cnt[i] = 0;
            base[i] = BB[i] + H[(size_t)i * ABLK + blockIdx.x];
        }
        __syncthreads();
        const int Et = E + N;
        for (int e = blockIdx.x * 256 + t; e < Et; e += ABLK * 256) {
            int s, d;
            if (e < E) { s = ei[e]; d = ei[E + e]; }
            else       { s = e - E; d = e - E; }
            const int b = d >> SHIFT;
            const int r = atomicAdd(&cnt[b], 1);
            E2[base[b] + r] = (unsigned)s | ((unsigned)(d & 255) << 24);
        }
        return;
    }

    // ---------------- GEMM1 (MFMA bf16x3) ----------------
    for (int i = t; i < 4096; i += 256)
        ((uint4*)Bs)[i] = ((const uint4*)W1s)[i];

    const int wm = t >> 6;
    const int l  = t & 63;
    const int wrow0 = (blockIdx.x - ABLK) * 64 + wm * 16;
    const int arow = wrow0 + (l & 15);
    const int rc = (arow < N) ? arow : (N - 1);

    short8 ah[4], al[4];
    #pragma unroll
    for (int kt = 0; kt < 4; ++kt) {
        const float* xp = x + (size_t)rc * 128 + kt * 32 + ((l >> 4) * 8);
        const float4 v0 = ((const float4*)xp)[0];
        const float4 v1 = ((const float4*)xp)[1];
        const float vv[8] = {v0.x, v0.y, v0.z, v0.w, v1.x, v1.y, v1.z, v1.w};
        #pragma unroll
        for (int e = 0; e < 8; ++e) {
            const unsigned short hi = f2bf(vv[e]);
            ((unsigned short*)&ah[kt])[e] = hi;
            ((unsigned short*)&al[kt])[e] = f2bf(vv[e] - bf2f(hi));
        }
    }
    __syncthreads();

    f32x4 acc[8] = {};
    #pragma unroll
    for (int kt = 0; kt < 4; ++kt) {
        #pragma unroll
        for (int nt = 0; nt < 8; ++nt) {
            const short8 bh = *(const short8*)(Bs + (kt * 8 + nt) * 512 + l * 8);
            const short8 bl = *(const short8*)(Bs + 16384 + (kt * 8 + nt) * 512 + l * 8);
            acc[nt] = __builtin_amdgcn_mfma_f32_16x16x32_bf16(ah[kt], bh, acc[nt], 0, 0, 0);
            acc[nt] = __builtin_amdgcn_mfma_f32_16x16x32_bf16(ah[kt], bl, acc[nt], 0, 0, 0);
            acc[nt] = __builtin_amdgcn_mfma_f32_16x16x32_bf16(al[kt], bh, acc[nt], 0, 0, 0);
        }
    }

    const int cl = l & 15;
    const int rbase = wrow0 + ((l >> 4) * 4);
    #pragma unroll
    for (int reg = 0; reg < 4; ++reg) {
        const int orow = rbase + reg;
        if (orow < N) {
            #pragma unroll
            for (int nt = 0; nt < 8; ++nt)
                xhb[(size_t)orow * 128 + nt * 16 + cl] = f2bf(acc[nt][reg]);
        }
    }
}

// ---- fused: bcsr w/ x8 sentinel padding (blocks [0,NBK)) + esed1 --------------
__global__ __launch_bounds__(256) void k_ce(const unsigned* __restrict__ E2,
                                            const int* __restrict__ BB, int N,
                                            int* __restrict__ deg,
                                            int* __restrict__ rowp,
                                            int* __restrict__ csr, int NBK,
                                            const unsigned short* __restrict__ xhb,
                                            const float* __restrict__ asrc,
                                            const float* __restrict__ adst,
                                            float* __restrict__ es,
                                            float* __restrict__ ed) {
    __shared__ int cnt[256];
    __shared__ int sc[256];
    __shared__ int rp[256];
    __shared__ int fl[256];
    const int t = threadIdx.x;

    if (blockIdx.x >= NBK) {
        // ---------------- esed1 (+ sentinel row at node N) ----------------
        const int i = (blockIdx.x - NBK) * 256 + t;
        if (i == 0) {
            #pragma unroll
            for (int h = 0; h < 8; ++h) es[N * 8 + h] = -1e30f;
        }
        if (i >= N * 8) return;
        const int h = i & 7;
        const uint4* p = (const uint4*)(xhb + (size_t)i * 16);
        const uint4 q0 = p[0], q1 = p[1];
        const unsigned w[8] = {q0.x, q0.y, q0.z, q0.w, q1.x, q1.y, q1.z, q1.w};
        const float* av = asrc + h * 16;
        const float* bv = adst + h * 16;
        float s = 0.f, d = 0.f;
        #pragma unroll
        for (int j = 0; j < 8; ++j) {
            const float v0 = bf_lo(w[j]);
            const float v1 = bf_hi(w[j]);
            s += v0 * av[2 * j] + v1 * av[2 * j + 1];
            d += v0 * bv[2 * j] + v1 * bv[2 * j + 1];
        }
        es[i] = s; ed[i] = d;
        return;
    }

    // ---------------- bcsr: rows padded to x8 with dummy src N ----------------
    const int b = blockIdx.x;
    const int lo = BB[b], hi = BB[b + 1];     // raw E2 range
    const int lo8 = lo + b * PADSLACK;        // padded csr base for this bucket
    const int base_d = b << SHIFT;
    cnt[t] = 0; fl[t] = 0;
    __syncthreads();
    for (int i = lo + t; i < hi; i += 256)
        atomicAdd(&cnt[E2[i] >> 24], 1);
    __syncthreads();
    const int v  = cnt[t];
    const int v8 = (v + 7) & ~7;
    sc[t] = v8;
    __syncthreads();
    for (int off = 1; off < 256; off <<= 1) {
        int add = (t >= off) ? sc[t - off] : 0;
        __syncthreads();
        sc[t] += add;
        __syncthreads();
    }
    rp[t] = sc[t] - v8;                        // exclusive scan of padded counts
    const int d = base_d + t;
    if (d < N) { deg[d] = v; rowp[d] = lo8 + rp[t]; }
    __syncthreads();
    for (int i = lo + t; i < hi; i += 256) {
        const unsigned e = E2[i];
        const int ld = e >> 24;
        const int r = atomicAdd(&fl[ld], 1);
        csr[lo8 + rp[ld] + r] = (int)(e & 0xFFFFFFu);
    }
    __syncthreads();
    if (d < N) {                               // fill sentinel pads
        for (int j = v; j < v8; ++j)
            csr[lo8 + rp[t] + j] = N;
    }
}

// -------- layer-1 aggregate: 8-edge tiles, sentinel-padded (no clamping) -------
__global__ __launch_bounds__(256) void k_l1(const unsigned short* __restrict__ xhb,
                                            const float* __restrict__ es,
                                            const float* __restrict__ ed,
                                            const int* __restrict__ rowp,
                                            const int* __restrict__ deg,
                                            const int* __restrict__ csr,
                                            const float* __restrict__ b1,
                                            unsigned short* __restrict__ hb, int N) {
    const int wave = threadIdx.x >> 6;
    const int lane = threadIdx.x & 63;
    const int n = blockIdx.x * 4 + wave;
    if (n >= N) return;
    const int hA = lane >> 3;
    const int eA = lane & 7;
    const float edv = ed[n * 8 + hA];
    const int start = rowp[n];
    const int cnt8 = (deg[n] + 7) & ~7;
    const int lane4 = lane * 4;

    float acc0 = 0.f, acc1 = 0.f, dpart = 0.f;
    const char* xb = (const char*)xhb;

    for (int k = 0; k < cnt8; k += 8) {
        const int s = csr[start + k + eA];
        const float a = lrelu_exp(es[s * 8 + hA] + edv);   // pads: exp(-1e30)=0
        dpart += a;
        const int soff = s << 8;
#define L1E(e) { \
        const float ae = swz_f<SWZ(e)>(a); \
        const int   ro = swz_i<SWZ(e)>(soff); \
        const unsigned pv = *(const unsigned*)(xb + (unsigned)(ro + lane4)); \
        acc0 += ae * bf_lo(pv); \
        acc1 += ae * bf_hi(pv); }
        L1E(0) L1E(1) L1E(2) L1E(3) L1E(4) L1E(5) L1E(6) L1E(7)
#undef L1E
    }
    dpart += __shfl_xor(dpart, 1, 64);
    dpart += __shfl_xor(dpart, 2, 64);
    dpart += __shfl_xor(dpart, 4, 64);

    const float inv = 1.f / (dpart + EPSF);
    const float2 bb = *(const float2*)(b1 + lane * 2);
    float o0 = acc0 * inv + bb.x;
    float o1 = acc1 * inv + bb.y;
    o0 = (o0 > 0.f) ? o0 : expm1f(o0);
    o1 = (o1 > 0.f) ? o1 : expm1f(o1);
    const unsigned pk = (unsigned)f2bf(o0) | ((unsigned)f2bf(o1) << 16);
    *(unsigned*)(hb + (size_t)n * 128 + lane * 2) = pk;
}

// ---- GEMM2 (MFMA, 64 rows/block) + fused e_src2/e_dst2 from f32 accs ----------
__global__ __launch_bounds__(256) void k_mm2(const unsigned short* __restrict__ h,
                                             const unsigned short* __restrict__ W2s,
                                             const float* __restrict__ as2,
                                             const float* __restrict__ ad2,
                                             unsigned short* __restrict__ xh2,
                                             float* __restrict__ es2,
                                             float* __restrict__ ed2, int N) {
    __shared__ unsigned short Bs[12288];     // 24 KB
    const int t = threadIdx.x;
    if (blockIdx.x == 0 && t == 0) es2[N] = -1e30f;   // sentinel for k_l2
    for (int i = t; i < 1536; i += 256)
        ((uint4*)Bs)[i] = ((const uint4*)W2s)[i];

    const int wm = t >> 6;
    const int l  = t & 63;
    const int wrow0 = blockIdx.x * 64 + wm * 16;
    const int arow = wrow0 + (l & 15);
    const int rc = (arow < N) ? arow : (N - 1);

    short8 a[4];
    #pragma unroll
    for (int kt = 0; kt < 4; ++kt)
        a[kt] = *(const short8*)(h + (size_t)rc * 128 + kt * 32 + ((l >> 4) * 8));
    __syncthreads();

    f32x4 acc[3] = {};
    #pragma unroll
    for (int kt = 0; kt < 4; ++kt) {
        #pragma unroll
        for (int nt = 0; nt < 3; ++nt) {
            const short8 bh = *(const short8*)(Bs + (kt * 3 + nt) * 512 + l * 8);
            const short8 bl = *(const short8*)(Bs + 6144 + (kt * 3 + nt) * 512 + l * 8);
            acc[nt] = __builtin_amdgcn_mfma_f32_16x16x32_bf16(a[kt], bh, acc[nt], 0, 0, 0);
            acc[nt] = __builtin_amdgcn_mfma_f32_16x16x32_bf16(a[kt], bl, acc[nt], 0, 0, 0);
        }
    }

    const int cl = l & 15;
    const int rbase = wrow0 + ((l >> 4) * 4);
    #pragma unroll
    for (int reg = 0; reg < 4; ++reg) {
        const int orow = rbase + reg;
        if (orow < N) {
            #pragma unroll
            for (int nt = 0; nt < 3; ++nt) {
                const int c = nt * 16 + cl;
                if (c < 40)
                    xh2[(size_t)orow * 64 + c] = f2bf(acc[nt][reg]);
            }
        }
    }

    // fused e_src2/e_dst2 (single head): reduce over the 16-lane col group
    const float a0 = as2[cl],      d0v = ad2[cl];
    const float a1 = as2[16 + cl], d1v = ad2[16 + cl];
    const float a2 = (cl < 8) ? as2[32 + cl] : 0.f;
    const float d2v = (cl < 8) ? ad2[32 + cl] : 0.f;
    #pragma unroll
    for (int reg = 0; reg < 4; ++reg) {
        float ps = acc[0][reg] * a0 + acc[1][reg] * a1 + acc[2][reg] * a2;
        float pd = acc[0][reg] * d0v + acc[1][reg] * d1v + acc[2][reg] * d2v;
        ps += __shfl_xor(ps, 1, 64); ps += __shfl_xor(ps, 2, 64);
        ps += __shfl_xor(ps, 4, 64); ps += __shfl_xor(ps, 8, 64);
        pd += __shfl_xor(pd, 1, 64); pd += __shfl_xor(pd, 2, 64);
        pd += __shfl_xor(pd, 4, 64); pd += __shfl_xor(pd, 8, 64);
        const int row = rbase + reg;
        if (cl == reg && row < N) {
            es2[row] = ps;
            ed2[row] = pd;
        }
    }
}

// ---- layer-2 aggregate: 2 nodes/wave, 4-edge tiles, sentinel-padded -----------
__global__ __launch_bounds__(256) void k_l2(const unsigned short* __restrict__ xh2,
                                            const float* __restrict__ es2,
                                            const float* __restrict__ ed2,
                                            const int* __restrict__ rowp,
                                            const int* __restrict__ deg,
                                            const int* __restrict__ csr,
                                            const float* __restrict__ b2,
                                            float* __restrict__ out, int N) {
    const int wave = threadIdx.x >> 6;
    const int lane = threadIdx.x & 63;
    const int half = lane >> 5;
    const int n0 = blockIdx.x * 8 + wave * 2;
    if (n0 >= N) return;
    int n = n0 + half;
    const bool valid = (n < N);
    if (!valid) n = N - 1;
    const float edv = ed2[n];
    const int start = rowp[n];
    const int cnt8 = (deg[n] + 7) & ~7;
    const int c8m1 = cnt8 - 1;
    const int eA = lane & 3;
    const int c2 = lane & 31;
    const int cc4 = ((c2 < 20) ? c2 : 19) * 4;
    const char* xb = (const char*)xh2;
    const int cmax = max(cnt8, __shfl_xor(cnt8, 32, 64));

    float acc0 = 0.f, acc1 = 0.f, dpart = 0.f;
    for (int k = 0; k < cmax; k += 4) {
        const int ke = k + eA;
        const int idx = start + min(ke, c8m1);   // in-bounds; may hit real edge
        const int s = csr[idx];
        float a = lrelu_exp(es2[s] + edv);
        a = (ke <= c8m1) ? a : 0.f;              // zero clamped duplicates (deg%8==0 case)
        dpart += a;
        const int soff = s << 7;
#define L2E(e) { \
        const float ae = swz_f<SWZ4(e)>(a); \
        const int   ro = swz_i<SWZ4(e)>(soff); \
        const unsigned pv = *(const unsigned*)(xb + (unsigned)(ro + cc4)); \
        acc0 += ae * bf_lo(pv); \
        acc1 += ae * bf_hi(pv); }
        L2E(0) L2E(1) L2E(2) L2E(3)
#undef L2E
    }
    dpart += __shfl_xor(dpart, 1, 64);
    dpart += __shfl_xor(dpart, 2, 64);

    if (valid && c2 < 20) {
        const float inv = 1.f / (dpart + EPSF);
        const float2 bb = *(const float2*)(b2 + c2 * 2);
        *(float2*)(out + (size_t)n * 40 + c2 * 2) =
            make_float2(acc0 * inv + bb.x, acc1 * inv + bb.y);
    }
}

extern "C" void kernel_launch(void* const* d_in, const int* in_sizes, int n_in,
                              void* d_out, int out_size, void* d_ws, size_t ws_size,
                              hipStream_t stream) {
    const float* x   = (const float*)d_in[0];
    const int*   ei  = (const int*)d_in[1];
    const float* W1  = (const float*)d_in[2];
    const float* as1 = (const float*)d_in[3];
    const float* ad1 = (const float*)d_in[4];
    const float* b1  = (const float*)d_in[5];
    const float* W2  = (const float*)d_in[6];
    const float* as2 = (const float*)d_in[7];
    const float* ad2 = (const float*)d_in[8];
    const float* b2  = (const float*)d_in[9];
    float* out = (float*)d_out;

    const int N   = in_sizes[0] / 128;
    const int E   = in_sizes[1] / 2;
    const int Et  = E + N;
    const int NBK = (N + 255) >> SHIFT;
    const int GBM = (N + 63) / 64;
    const int EB1 = (N * 8 + 255) / 256;

    // ---- workspace layout (xhb/xh2/es1 carry a sentinel row at index N) ----
    char* p = (char*)d_ws;
    unsigned short* W1s = (unsigned short*)p; p += 32768 * 2;   // 64 KB
    unsigned short* W2s = (unsigned short*)p; p += 12288 * 2;   // 24 KB
    unsigned short* xhb = (unsigned short*)p; p += (size_t)(N + 1) * 128 * 2;
    float* es1  = (float*)p; p += (size_t)(N + 1) * 8 * 4;
    float* ed1  = (float*)p; p += (size_t)N * 8 * 4;
    int*   deg  = (int*)p;   p += (size_t)N * 4;
    int*   rowp = (int*)p;   p += (size_t)N * 4;
    int*   csr  = (int*)p;   p += ((size_t)Et + (size_t)NBK * PADSLACK) * 4;
    int*   H    = (int*)p;   p += (size_t)512 * ABLK * 4;
    int*   BT   = (int*)p;   p += 512 * 4;
    int*   BB   = (int*)p;   p += 512 * 4;
    unsigned short* hbuf = (unsigned short*)p; p += (size_t)N * 128 * 2;
    unsigned short* xh2  = (unsigned short*)p; p += (size_t)(N + 1) * 64 * 2;
    unsigned* E2 = (unsigned*)hbuf;   // 6.8 MB < 25.6 MB; dead after k_ce
    float* es2 = es1;                 // es1 dead after k_l1; es2[N] = sentinel
    float* ed2 = ed1;

    k_ph    <<<ABLK + 88,    256, 0, stream>>>(ei, E, N, NBK, H, W1, W2, W1s, W2s);
    k_scanH <<<NBK,          512, 0, stream>>>(H, BT);
    k_scanBT<<<1,            512, 0, stream>>>(BT, BB, NBK);
    k_sm    <<<ABLK + GBM,   256, 0, stream>>>(ei, E, N, NBK, H, BB, E2, x, W1s, xhb);
    k_ce    <<<NBK + EB1,    256, 0, stream>>>(E2, BB, N, deg, rowp, csr, NBK,
                                               xhb, as1, ad1, es1, ed1);
    k_l1    <<<(N + 3) / 4,  256, 0, stream>>>(xhb, es1, ed1, rowp, deg, csr, b1, hbuf, N);
    k_mm2   <<<GBM,          256, 0, stream>>>(hbuf, W2s, as2, ad2, xh2, es2, ed2, N);
    k_l2    <<<(N + 7) / 8,  256, 0, stream>>>(xh2, es2, ed2, rowp, deg, csr, b2, out, N);
}